// Round 3
// baseline (360.427 us; speedup 1.0000x reference)
//
#include <hip/hip_runtime.h>
#include <hip/hip_bf16.h>
#include <stddef.h>

// Problem constants
#define B_   64
#define C_   1024
#define CB_  256
#define T_   512
#define G_   8
#define N_   32768          // B_*T_
#define EPS_ 1e-5f

using short8  = __attribute__((ext_vector_type(8))) short;
using short4v = __attribute__((ext_vector_type(4))) short;
using f32x4   = __attribute__((ext_vector_type(4))) float;

__device__ __forceinline__ short f2bf(float f) {
    unsigned u = __float_as_uint(f);
    u += 0x7fffu + ((u >> 16) & 1u);   // RNE
    return (short)(u >> 16);
}

__device__ __forceinline__ float mish_f(float y) {
    // mish(y) = y * tanh(softplus(y)) = y * (u^2+2u)/(u^2+2u+2), u = e^y
    float u = __expf(fminf(y, 30.f));
    float w = u * u + 2.f * u;
    return y * (w / (w + 2.f));
}

// ---------------- Kernel 0: weights fp32 -> bf16, MFMA-fragment-tiled ----------------
// Both GEMM A-operands are read directly from global (L2-resident) as 1 KB/wave
// coalesced fragments; no LDS staging for A in either phase.
// wd [CB_=256 m][C_=1024 k] -> wdt: (m,k) -> ((m/16)*32 + k/32)*512 + ((k/8)%4)*128 + (m%16)*8 + k%8
// wu [C_=1024 m][CB_=256 k] -> wut: (m,k) -> ((m/16)*8  + k/32)*512 + ((k/8)%4)*128 + (m%16)*8 + k%8
__global__ void prep_weights(const float* __restrict__ wd, const float* __restrict__ wu,
                             short* __restrict__ wdt, short* __restrict__ wut) {
    int i = blockIdx.x * 256 + threadIdx.x;
    if (i < CB_ * C_) {
        {
            int m = i >> 10, k = i & 1023;
            int idx = (((m >> 4) * 32 + (k >> 5)) << 9) + (((k >> 3) & 3) << 7)
                    + ((m & 15) << 3) + (k & 7);
            wdt[idx] = f2bf(wd[i]);
        }
        {
            int m = i >> 8, k = i & 255;
            int idx = (((m >> 4) * 8 + (k >> 5)) << 9) + (((k >> 3) & 3) << 7)
                    + ((m & 15) << 3) + (k & 7);
            wut[idx] = f2bf(wu[i]);
        }
    }
}

// ---------------- Kernel 1: group stats + NORMALIZE -> bf16 xh ----------------
// Pass 1: mean/var reduction (unchanged). Pass 2: re-read the block's 256 KB
// slice (L2/L3-hot) and write xh = f2bf(x*sc+sh) -- the exact expression the
// old fused staging computed, so results are bit-identical, but the fused
// kernel now reads 2 B/elem instead of 4 B/elem.
__global__ void stats_kernel(const float* __restrict__ x, const float* __restrict__ gamma,
                             const float* __restrict__ beta, short* __restrict__ xh) {
    const int tid = threadIdx.x;
    const int bg = blockIdx.x;
    const int b = bg >> 3, g = bg & 7;
    const size_t base = ((size_t)b * C_ + g * 128) * T_;
    const float4* p = (const float4*)(x + base);
    float s = 0.f, q = 0.f;
    for (int i = tid; i < 16384; i += 256) {
        float4 v = p[i];
        s += v.x + v.y + v.z + v.w;
        q += v.x * v.x + v.y * v.y + v.z * v.z + v.w * v.w;
    }
    for (int o = 32; o > 0; o >>= 1) {
        s += __shfl_down(s, o);
        q += __shfl_down(q, o);
    }
    __shared__ float red[8];
    __shared__ float mr[2];
    __shared__ float sls[128], slt[128];
    const int wid = tid >> 6, lane = tid & 63;
    if (lane == 0) { red[wid] = s; red[4 + wid] = q; }
    __syncthreads();
    if (tid == 0) {
        float S = red[0] + red[1] + red[2] + red[3];
        float Q = red[4] + red[5] + red[6] + red[7];
        float mean = S * (1.f / 65536.f);
        float var = Q * (1.f / 65536.f) - mean * mean;
        mr[0] = mean;
        mr[1] = rsqrtf(var + EPS_);
    }
    __syncthreads();
    if (tid < 128) {
        int c = g * 128 + tid;
        float sc = mr[1] * gamma[c];
        sls[tid] = sc;
        slt[tid] = beta[c] - mr[0] * sc;
    }
    __syncthreads();
    short4v* xq = (short4v*)(xh + base);
    for (int i = tid; i < 16384; i += 256) {
        float4 v = p[i];
        const int cl = i >> 7;
        const float sc = sls[cl], sh = slt[cl];
        short4v o;
        o[0] = f2bf(v.x * sc + sh);
        o[1] = f2bf(v.y * sc + sh);
        o[2] = f2bf(v.z * sc + sh);
        o[3] = f2bf(v.w * sc + sh);
        xq[i] = o;
    }
}

// LDS row stride 40 bf16 (80 B): ~2-way (free) for b128 fragment reads.
#define LDSTR 40
// mid-tile stride: 256 k + 8 pad = 264 shorts (528 B): aligned b128, ~2-way.
#define MSTR  264

// Raw barrier: drain only our LDS ops (writer side); global loads stay in flight.
#define BAR() { asm volatile("s_waitcnt lgkmcnt(0)" ::: "memory"); __builtin_amdgcn_s_barrier(); }

// ---------------- Kernel 2: FUSED  GEMM1(bf16 xh) -> mish -> GEMM2 -> +resid ----
// One block per n-tile of 128 (grid = 256 = 1 block/CU), 512 threads = 8 waves.
// Phase A: M=256, K=1024, BK=32. B (=normalized x) staged in double-buffered
//   LDS from bf16 xh (8 KB/step); A fragments read straight from L2 (wdt) with
//   1-step register prefetch; 1 raw barrier per K-step, no vmcnt(0) drains.
// Epilogue A: +b_down, mish, bf16 -> LDS Ms[n][k] (128 x 264).
// Phase B: M=1024, K=256(all in LDS), N=128; A fragments from L2 (wut).
__global__ __launch_bounds__(512, 2) void fused_adapter(
    const short* __restrict__ xh, const float* __restrict__ x,
    const short* __restrict__ wdt, const float* __restrict__ b_down,
    const short* __restrict__ wut, const float* __restrict__ b_up,
    float* __restrict__ out) {
    __shared__ short Bs0[128 * LDSTR];  // 10.0 KB
    __shared__ short Bs1[128 * LDSTR];  // 10.0 KB
    __shared__ short Ms[128 * MSTR];    // 66.0 KB   (total 86 KB, 1 block/CU)

    const int tid = threadIdx.x;
    const int n0 = blockIdx.x * 128;
    const int b  = n0 >> 9;
    const int t0 = n0 & 511;

    // B staging: 128 n x 32 k bf16; thread: n=b_n, k octet b_kg*8
    const int b_n  = tid & 127;
    const int b_kg = tid >> 7;          // 0..3
    const int wid  = tid >> 6;
    const int lane = tid & 63;
    const int wm = wid >> 1, wn = wid & 1;   // wm 0..3, wn 0..1
    const int q = lane >> 4, l16 = lane & 15;

    f32x4 acc[4][4];
#pragma unroll
    for (int i = 0; i < 4; i++)
#pragma unroll
        for (int j = 0; j < 4; j++) acc[i][j] = 0.f;

    const unsigned short* xhb = (const unsigned short*)xh + (size_t)b * C_ * T_ + t0;

#define ISSUE_B(kt, bb) { \
    const unsigned short* xp = xhb + (size_t)((kt) * 32 + b_kg * 8) * T_ + b_n; \
    _Pragma("unroll") for (int i_ = 0; i_ < 8; i_++) bb[i_] = xp[(size_t)i_ * T_]; }

#define STORE_B(Bs_, bb) { \
    short8 v_; \
    _Pragma("unroll") for (int i_ = 0; i_ < 8; i_++) v_[i_] = (short)bb[i_]; \
    *(short8*)&Bs_[b_n * LDSTR + b_kg * 8] = v_; }

#define AFRAG(kt, ff) { \
    _Pragma("unroll") for (int i_ = 0; i_ < 4; i_++) \
        ff[i_] = *(const short8*)(wdt + ((size_t)((wm * 4 + i_) * 32 + (kt)) << 9) + lane * 8); }

#define MFMA_STEP(Bs_, ff) { \
    short8 bf_[4]; \
    _Pragma("unroll") for (int j_ = 0; j_ < 4; j_++) \
        bf_[j_] = *(const short8*)&Bs_[(wn * 64 + j_ * 16 + l16) * LDSTR + q * 8]; \
    _Pragma("unroll") for (int i_ = 0; i_ < 4; i_++) \
    _Pragma("unroll") for (int j_ = 0; j_ < 4; j_++) \
        acc[i_][j_] = __builtin_amdgcn_mfma_f32_16x16x32_bf16(ff[i_], bf_[j_], acc[i_][j_], 0, 0, 0); }

    // ---- phase A prologue ----
    unsigned short bvA[8], bvB[8];
    short8 fA[4], fB[4];
    AFRAG(0, fA);
    ISSUE_B(0, bvA);
    ISSUE_B(1, bvB);
    AFRAG(1, fB);
    STORE_B(Bs0, bvA);           // counted vmcnt wait on bvA only
    BAR();                       // Bs0 ready

#pragma unroll 1
    for (int kt2 = 0; kt2 < 16; ++kt2) {
        const int kt = kt2 * 2;
        // even step: compute buf0(kt); issue xh(kt+2), frags(kt+2); stage kt+1 -> buf1
        if (kt + 2 < 32) ISSUE_B(kt + 2, bvA);
        MFMA_STEP(Bs0, fA);
        if (kt + 2 < 32) AFRAG(kt + 2, fA);
        STORE_B(Bs1, bvB);
        BAR();
        // odd step: compute buf1(kt+1); issue xh(kt+3), frags(kt+3); stage kt+2 -> buf0
        if (kt + 3 < 32) ISSUE_B(kt + 3, bvB);
        MFMA_STEP(Bs1, fB);
        if (kt + 3 < 32) AFRAG(kt + 3, fB);
        if (kt + 2 < 32) STORE_B(Bs0, bvA);
        BAR();
    }

    // ---- epilogue A: + b_down, mish, bf16 -> Ms[n][k]  (k = Cb index) ----
#pragma unroll
    for (int i = 0; i < 4; i++) {
        const int o_b = wm * 64 + i * 16 + q * 4;
        const float bd0 = b_down[o_b];
        const float bd1 = b_down[o_b + 1];
        const float bd2 = b_down[o_b + 2];
        const float bd3 = b_down[o_b + 3];
#pragma unroll
        for (int j = 0; j < 4; j++) {
            const int nl = wn * 64 + j * 16 + l16;
            short4v v;
            v[0] = f2bf(mish_f(acc[i][j][0] + bd0));
            v[1] = f2bf(mish_f(acc[i][j][1] + bd1));
            v[2] = f2bf(mish_f(acc[i][j][2] + bd2));
            v[3] = f2bf(mish_f(acc[i][j][3] + bd3));
            *(short4v*)&Ms[nl * MSTR + o_b] = v;
        }
    }
    BAR();   // Ms fully written

    // ---- phase B: out[c, ttile] = wu[c,:] . Ms[:, n] + b_up + resid ----
    // Each wave owns 64 m-rows x 128 n per half; 2 halves -> M=1024.
#pragma unroll 1
    for (int half = 0; half < 2; ++half) {
        f32x4 a2[4][8];
#pragma unroll
        for (int i = 0; i < 4; i++)
#pragma unroll
            for (int j = 0; j < 8; j++) a2[i][j] = 0.f;

        const int mbb = half * 32 + wid * 4;     // m-tile-of-16 base index
#pragma unroll 2
        for (int kt = 0; kt < 8; ++kt) {
            short8 af[4], bf2[8];
#pragma unroll
            for (int i = 0; i < 4; i++)
                af[i] = *(const short8*)(wut + ((size_t)((mbb + i) * 8 + kt) << 9) + lane * 8);
#pragma unroll
            for (int j = 0; j < 8; j++)
                bf2[j] = *(const short8*)&Ms[(j * 16 + l16) * MSTR + kt * 32 + q * 8];
#pragma unroll
            for (int i = 0; i < 4; i++)
#pragma unroll
                for (int j = 0; j < 8; j++)
                    a2[i][j] = __builtin_amdgcn_mfma_f32_16x16x32_bf16(af[i], bf2[j], a2[i][j], 0, 0, 0);
        }

        // epilogue B: + b_up[c] + x residual, fp32 store
#pragma unroll
        for (int i = 0; i < 4; i++) {
            const int c_b = half * 512 + wid * 64 + i * 16 + q * 4;
            const float bu0 = b_up[c_b];
            const float bu1 = b_up[c_b + 1];
            const float bu2 = b_up[c_b + 2];
            const float bu3 = b_up[c_b + 3];
#pragma unroll
            for (int j = 0; j < 8; j++) {
                const int tt = t0 + j * 16 + l16;
                const size_t gi = ((size_t)b * C_ + c_b) * T_ + tt;
                out[gi]              = a2[i][j][0] + bu0 + x[gi];
                out[gi + T_]         = a2[i][j][1] + bu1 + x[gi + T_];
                out[gi + 2 * T_]     = a2[i][j][2] + bu2 + x[gi + 2 * T_];
                out[gi + 3 * T_]     = a2[i][j][3] + bu3 + x[gi + 3 * T_];
            }
        }
    }
#undef ISSUE_B
#undef STORE_B
#undef AFRAG
#undef MFMA_STEP
}

// ---------------- Launch ----------------
extern "C" void kernel_launch(void* const* d_in, const int* in_sizes, int n_in,
                              void* d_out, int out_size, void* d_ws, size_t ws_size,
                              hipStream_t stream) {
    const float* x      = (const float*)d_in[0];
    const float* gamma  = (const float*)d_in[1];
    const float* beta   = (const float*)d_in[2];
    const float* w_down = (const float*)d_in[3];
    const float* b_down = (const float*)d_in[4];
    const float* w_up   = (const float*)d_in[5];
    const float* b_up   = (const float*)d_in[6];
    float* out = (float*)d_out;

    short* xh  = (short*)d_ws;                 // B_*C_*T_ bf16 normalized (67 MB)
    short* wdt = xh + (size_t)B_ * C_ * T_;    // CB_*C_ bf16 (fragment-tiled)
    short* wut = wdt + CB_ * C_;               // C_*CB_ bf16 (fragment-tiled)

    prep_weights<<<dim3((CB_ * C_ + 255) / 256), 256, 0, stream>>>(w_down, w_up, wdt, wut);
    stats_kernel<<<dim3(B_ * G_), 256, 0, stream>>>(x, gamma, beta, xh);
    fused_adapter<<<dim3(N_ / 128), 512, 0, stream>>>(xh, x, wdt, b_down, wut, b_up, out);
}

// Round 5
// 318.569 us; speedup vs baseline: 1.1314x; 1.1314x over previous
//
#include <hip/hip_runtime.h>
#include <hip/hip_bf16.h>
#include <stddef.h>

// Problem constants
#define B_   64
#define C_   1024
#define CB_  256
#define T_   512
#define G_   8
#define N_   32768          // B_*T_
#define EPS_ 1e-5f

using short8  = __attribute__((ext_vector_type(8))) short;
using short4v = __attribute__((ext_vector_type(4))) short;
using f32x4   = __attribute__((ext_vector_type(4))) float;

__device__ __forceinline__ short f2bf(float f) {
    unsigned u = __float_as_uint(f);
    u += 0x7fffu + ((u >> 16) & 1u);   // RNE
    return (short)(u >> 16);
}

__device__ __forceinline__ float mish_f(float y) {
    // mish(y) = y * tanh(softplus(y)) = y * (u^2+2u)/(u^2+2u+2), u = e^y
    float u = __expf(fminf(y, 30.f));
    float w = u * u + 2.f * u;
    return y * (w / (w + 2.f));
}

// ---------------- Kernel 0: weights fp32 -> bf16 ----------------
// wd -> wdb: plain [CB_][C_] bf16 (phase-A LDS staging layout).
// wu -> wut: MFMA-fragment-tiled bf16; in phase B it is consumed as the
//            B-operand (lane l16 = wu row = c, q = k-octet):
//   (m,k) -> ((m/16)*8 + k/32)*512 + ((k/8)%4)*128 + (m%16)*8 + (k%8)
__global__ void prep_weights(const float* __restrict__ wd, const float* __restrict__ wu,
                             short* __restrict__ wdb, short* __restrict__ wut) {
    int i = blockIdx.x * 256 + threadIdx.x;
    if (i < CB_ * C_) {
        wdb[i] = f2bf(wd[i]);
        int m = i >> 8, k = i & 255;        // wu is [C_=1024][CB_=256]
        int idx = (((m >> 4) * 8 + (k >> 5)) << 9) + (((k >> 3) & 3) << 7)
                + ((m & 15) << 3) + (k & 7);
        wut[idx] = f2bf(wu[i]);
    }
}

// ---------------- Kernel 1: group stats -> per-(b,c) scale/shift ----------------
__global__ void stats_kernel(const float* __restrict__ x, const float* __restrict__ gamma,
                             const float* __restrict__ beta,
                             float* __restrict__ scaleW, float* __restrict__ shiftW) {
    const int tid = threadIdx.x;
    const int bg = blockIdx.x;
    const int b = bg >> 3, g = bg & 7;
    const float4* p = (const float4*)(x + ((size_t)b * C_ + g * 128) * T_);
    float s = 0.f, q = 0.f;
    for (int i = tid; i < 16384; i += 256) {
        float4 v = p[i];
        s += v.x + v.y + v.z + v.w;
        q += v.x * v.x + v.y * v.y + v.z * v.z + v.w * v.w;
    }
    for (int o = 32; o > 0; o >>= 1) {
        s += __shfl_down(s, o);
        q += __shfl_down(q, o);
    }
    __shared__ float red[8];
    __shared__ float mr[2];
    const int wid = tid >> 6, lane = tid & 63;
    if (lane == 0) { red[wid] = s; red[4 + wid] = q; }
    __syncthreads();
    if (tid == 0) {
        float S = red[0] + red[1] + red[2] + red[3];
        float Q = red[4] + red[5] + red[6] + red[7];
        float mean = S * (1.f / 65536.f);
        float var = Q * (1.f / 65536.f) - mean * mean;
        mr[0] = mean;
        mr[1] = rsqrtf(var + EPS_);
    }
    __syncthreads();
    float mean = mr[0], rstd = mr[1];
    if (tid < 128) {
        int c = g * 128 + tid;
        float sc = rstd * gamma[c];
        scaleW[b * C_ + c] = sc;
        shiftW[b * C_ + c] = beta[c] - mean * sc;
    }
}

// LDS row stride 40 bf16 (80 B): ~2-way (free) for b128 fragment reads.
#define LDSTR 40
// mid-tile stride: 256 k + 8 pad = 264 shorts (528 B): aligned b128, ~2-way.
#define MSTR  264

// Raw barrier: drain only our LDS ops (writer side); global loads stay in flight.
#define BAR() { asm volatile("s_waitcnt lgkmcnt(0)" ::: "memory"); __builtin_amdgcn_s_barrier(); }

// ---------------- Kernel 2: FUSED  GN -> GEMM1 -> mish -> GEMM2 -> +resid ----
// One block per n-tile of 128 (grid = 256 = 1 block/CU), 512 threads = 8 waves.
// Phase A (verified round-2 structure): M=256, K=1024, BK=32, double-buffered
//   LDS, 1 raw barrier per K-step, 2-deep register prefetch, no vmcnt(0) drains.
// Epilogue A: +b_down, mish, bf16 -> LDS Ms[n][k] (128 x 264).
// Phase B (operand-swapped): D[t][c] = Ms(A-op) x wut(B-op); reg index walks
//   4 consecutive t -> float4 residual loads + float4 out stores.
__global__ __launch_bounds__(512, 2) void fused_adapter(
    const float* __restrict__ x, const short* __restrict__ wd,
    const float* __restrict__ b_down,
    const float* __restrict__ scaleW, const float* __restrict__ shiftW,
    const short* __restrict__ wut, const float* __restrict__ b_up,
    float* __restrict__ out) {
    __shared__ short As0[256 * LDSTR];  // 20.0 KB
    __shared__ short As1[256 * LDSTR];  // 20.0 KB
    __shared__ short Bs0[128 * LDSTR];  // 10.0 KB
    __shared__ short Bs1[128 * LDSTR];  // 10.0 KB
    __shared__ float sS[C_], sT[C_];    //  8.0 KB
    __shared__ short Ms[128 * MSTR];    // 66.0 KB   (total 134 KB, 1 block/CU)

    const int tid = threadIdx.x;
    const int n0 = blockIdx.x * 128;
    const int b  = n0 >> 9;
    const int t0 = n0 & 511;

    for (int i = tid; i < C_; i += 512) {
        sS[i] = scaleW[b * C_ + i];
        sT[i] = shiftW[b * C_ + i];
    }

    // A staging: 256 rows x 4 k-chunks(8) = 1024 short8; 512 thr -> 2 each
    const int a_kc = tid & 3;
    const int a_m  = tid >> 2;          // 0..127 (rows a_m, a_m+128)
    // B staging: 128 n x 32 k floats; thread: n=b_n, k octet b_kg*8
    const int b_n  = tid & 127;
    const int b_kg = tid >> 7;          // 0..3
    const int wid  = tid >> 6;
    const int lane = tid & 63;
    const int wm = wid >> 1, wn = wid & 1;   // wm 0..3, wn 0..1
    const int q = lane >> 4, l16 = lane & 15;

    f32x4 acc[4][4];
#pragma unroll
    for (int i = 0; i < 4; i++)
#pragma unroll
        for (int j = 0; j < 4; j++) acc[i][j] = 0.f;

    const float* xb = x + (size_t)b * C_ * T_ + t0;

#define ISSUE(kt, aa0, aa1, bb) { \
    const short* src = wd + a_m * C_ + (kt) * 32 + a_kc * 8; \
    aa0 = *(const short8*)src; \
    aa1 = *(const short8*)(src + 128 * C_); \
    const float* xp = xb + (size_t)((kt) * 32 + b_kg * 8) * T_ + b_n; \
    _Pragma("unroll") for (int i_ = 0; i_ < 8; i_++) bb[i_] = xp[(size_t)i_ * T_]; }

#define STORE(kt, As_, Bs_, aa0, aa1, bb) { \
    *(short8*)&As_[a_m * LDSTR + a_kc * 8] = aa0; \
    *(short8*)&As_[(a_m + 128) * LDSTR + a_kc * 8] = aa1; \
    const int kb_ = (kt) * 32 + b_kg * 8; \
    short8 v_; \
    _Pragma("unroll") for (int i_ = 0; i_ < 8; i_++) v_[i_] = f2bf(bb[i_] * sS[kb_ + i_] + sT[kb_ + i_]); \
    *(short8*)&Bs_[b_n * LDSTR + b_kg * 8] = v_; }

#define MFMA_STEP(As_, Bs_) { \
    short8 af_[4], bf_[4]; \
    _Pragma("unroll") for (int i_ = 0; i_ < 4; i_++) \
        af_[i_] = *(const short8*)&As_[(wm * 64 + i_ * 16 + l16) * LDSTR + q * 8]; \
    _Pragma("unroll") for (int j_ = 0; j_ < 4; j_++) \
        bf_[j_] = *(const short8*)&Bs_[(wn * 64 + j_ * 16 + l16) * LDSTR + q * 8]; \
    _Pragma("unroll") for (int i_ = 0; i_ < 4; i_++) \
    _Pragma("unroll") for (int j_ = 0; j_ < 4; j_++) \
        acc[i_][j_] = __builtin_amdgcn_mfma_f32_16x16x32_bf16(af_[i_], bf_[j_], acc[i_][j_], 0, 0, 0); }

    // ---- phase A prologue ----
    short8 a0A, a1A, a0B, a1B;
    float bvA[8], bvB[8];
    ISSUE(0, a0A, a1A, bvA);
    ISSUE(1, a0B, a1B, bvB);
    BAR();                       // sS/sT visible to all waves
    STORE(0, As0, Bs0, a0A, a1A, bvA);   // counted vmcnt wait on rA only
    BAR();                       // buf0 ready

#pragma unroll 1
    for (int kt2 = 0; kt2 < 16; ++kt2) {
        const int kt = kt2 * 2;
        // even step: compute buf0(kt), stage kt+1 -> buf1, issue kt+2 -> rA
        if (kt + 2 < 32) ISSUE(kt + 2, a0A, a1A, bvA);
        MFMA_STEP(As0, Bs0);
        STORE(kt + 1, As1, Bs1, a0B, a1B, bvB);
        BAR();
        // odd step: compute buf1(kt+1), stage kt+2 -> buf0, issue kt+3 -> rB
        if (kt + 3 < 32) ISSUE(kt + 3, a0B, a1B, bvB);
        MFMA_STEP(As1, Bs1);
        if (kt + 2 < 32) STORE(kt + 2, As0, Bs0, a0A, a1A, bvA);
        BAR();
    }

    // ---- epilogue A: + b_down, mish, bf16 -> Ms[n][k]  (k = Cb index) ----
#pragma unroll
    for (int i = 0; i < 4; i++) {
        const int o_b = wm * 64 + i * 16 + q * 4;
        const float bd0 = b_down[o_b];
        const float bd1 = b_down[o_b + 1];
        const float bd2 = b_down[o_b + 2];
        const float bd3 = b_down[o_b + 3];
#pragma unroll
        for (int j = 0; j < 4; j++) {
            const int nl = wn * 64 + j * 16 + l16;
            short4v v;
            v[0] = f2bf(mish_f(acc[i][j][0] + bd0));
            v[1] = f2bf(mish_f(acc[i][j][1] + bd1));
            v[2] = f2bf(mish_f(acc[i][j][2] + bd2));
            v[3] = f2bf(mish_f(acc[i][j][3] + bd3));
            *(short4v*)&Ms[nl * MSTR + o_b] = v;
        }
    }
    BAR();   // Ms fully written

    // ---- phase B (operand-swapped): out[c][t] tile = (Ms x wu^T)[t][c] ----
    // Per half: wave computes 128 t x 64 c.  A-op = Ms frag (lane=t, q=k-oct),
    // B-op = wut frag (lane=c, q=k-oct).  D: row=q*4+r -> t, col=l16 -> c.
#pragma unroll 1
    for (int half = 0; half < 2; ++half) {
        f32x4 a2[8][4];     // [tj][ci]
#pragma unroll
        for (int tj = 0; tj < 8; tj++)
#pragma unroll
            for (int ci = 0; ci < 4; ci++) a2[tj][ci] = 0.f;

        const int ctb = wid * 8 + half * 4;   // c-tile (of 16) base index
#pragma unroll 2
        for (int kt = 0; kt < 8; ++kt) {
            short8 af[8], bf2[4];
#pragma unroll
            for (int tj = 0; tj < 8; tj++)
                af[tj] = *(const short8*)&Ms[(tj * 16 + l16) * MSTR + kt * 32 + q * 8];
#pragma unroll
            for (int ci = 0; ci < 4; ci++)
                bf2[ci] = *(const short8*)(wut + ((size_t)((ctb + ci) * 8 + kt) << 9) + lane * 8);
#pragma unroll
            for (int tj = 0; tj < 8; tj++)
#pragma unroll
                for (int ci = 0; ci < 4; ci++)
                    a2[tj][ci] = __builtin_amdgcn_mfma_f32_16x16x32_bf16(af[tj], bf2[ci], a2[tj][ci], 0, 0, 0);
        }

        // epilogue B: float4 residual load + float4 store along t
#pragma unroll
        for (int ci = 0; ci < 4; ci++) {
            const int c = (ctb + ci) * 16 + l16;
            const float bu = b_up[c];
            const size_t rowb = ((size_t)b * C_ + c) * T_ + t0 + q * 4;
#pragma unroll
            for (int tj = 0; tj < 8; tj++) {
                const size_t gi = rowb + tj * 16;
                float4 xr = *(const float4*)(x + gi);
                float4 o;
                o.x = a2[tj][ci][0] + bu + xr.x;
                o.y = a2[tj][ci][1] + bu + xr.y;
                o.z = a2[tj][ci][2] + bu + xr.z;
                o.w = a2[tj][ci][3] + bu + xr.w;
                *(float4*)(out + gi) = o;
            }
        }
    }
#undef ISSUE
#undef STORE
#undef MFMA_STEP
}

// ---------------- Launch ----------------
extern "C" void kernel_launch(void* const* d_in, const int* in_sizes, int n_in,
                              void* d_out, int out_size, void* d_ws, size_t ws_size,
                              hipStream_t stream) {
    const float* x      = (const float*)d_in[0];
    const float* gamma  = (const float*)d_in[1];
    const float* beta   = (const float*)d_in[2];
    const float* w_down = (const float*)d_in[3];
    const float* b_down = (const float*)d_in[4];
    const float* w_up   = (const float*)d_in[5];
    const float* b_up   = (const float*)d_in[6];
    float* out = (float*)d_out;

    float* scaleW = (float*)d_ws;                       // B_*C_ floats
    float* shiftW = scaleW + B_ * C_;                   // B_*C_ floats
    short* wdb    = (short*)(shiftW + B_ * C_);         // CB_*C_ bf16
    short* wut    = wdb + CB_ * C_;                     // C_*CB_ bf16 (fragment-tiled)

    prep_weights<<<dim3((CB_ * C_ + 255) / 256), 256, 0, stream>>>(w_down, w_up, wdb, wut);
    stats_kernel<<<dim3(B_ * G_), 256, 0, stream>>>(x, gamma, beta, scaleW, shiftW);
    fused_adapter<<<dim3(N_ / 128), 512, 0, stream>>>(x, wdb, b_down, scaleW, shiftW,
                                                      wut, b_up, out);
}